// Round 3
// baseline (377.620 us; speedup 1.0000x reference)
//
#include <hip/hip_runtime.h>
#include <hip/hip_bf16.h>

typedef __attribute__((ext_vector_type(8))) short short8;
typedef __attribute__((ext_vector_type(4))) float floatx4;

constexpr int Bsz = 4, Ssz = 1024, NXc = 1024, NHc = 16, HDc = 64;
constexpr int OUT_ELEMS  = Bsz * Ssz * NXc;        // 4194304 floats
constexpr int HEAD_ELEMS = Bsz * NHc * Ssz * HDc;  // 4194304

union BF8 { __hip_bfloat16 h[8]; uint4 v; };

// load 8 fp32, round to bf16, return as 16B packet
__device__ inline uint4 cvt8(const float* __restrict__ p) {
    float4 a = *reinterpret_cast<const float4*>(p);
    float4 b = *reinterpret_cast<const float4*>(p + 4);
    BF8 u;
    u.h[0] = __float2bfloat16(a.x); u.h[1] = __float2bfloat16(a.y);
    u.h[2] = __float2bfloat16(a.z); u.h[3] = __float2bfloat16(a.w);
    u.h[4] = __float2bfloat16(b.x); u.h[5] = __float2bfloat16(b.y);
    u.h[6] = __float2bfloat16(b.z); u.h[7] = __float2bfloat16(b.w);
    return u.v;
}

// ---------------------------------------------------------------------------
// 64x64-tile GEMM, BK=32, 256 threads (4 waves). bf16 MFMA, fp32 acc/IO.
// EPI==0: A = fp32 x. QKV epilogue: q -> out0 fp32 (ld 1024),
//         k/v -> present fp32 [2][b][h][s][d].
// EPI==1: A = bf16 a_ws. Plain fp32 row-major epilogue (ld N).
// ---------------------------------------------------------------------------
template <int EPI>
__global__ __launch_bounds__(256) void gemm64(
    const void* __restrict__ Av,        // M x K row-major
    const float* __restrict__ Bw,       // K x N row-major, fp32
    const float* __restrict__ bias,     // N, fp32
    float* __restrict__ out0,
    float* __restrict__ present,
    int M, int N, int K)
{
    __shared__ __align__(16) __hip_bfloat16 As[64][40]; // [m][k]
    __shared__ __align__(16) __hip_bfloat16 Bs[64][40]; // [n][k]

    const int tid  = threadIdx.x;
    const int wave = tid >> 6, lane = tid & 63;
    const int quad = lane >> 4, l16 = lane & 15;
    const int m0 = blockIdx.y * 64, n0 = blockIdx.x * 64;
    const int mb = (wave >> 1) * 32, nb = (wave & 1) * 32;

    const int arow = tid >> 2, aseg = tid & 3; // 64 rows x 4 segs of 8
    const int brow = tid >> 3, bseg = tid & 7; // 32 krows x 8 nsegs of 8

    floatx4 acc[2][2];
#pragma unroll
    for (int i = 0; i < 2; ++i)
#pragma unroll
        for (int j = 0; j < 2; ++j)
#pragma unroll
            for (int r = 0; r < 4; ++r) acc[i][j][r] = 0.f;

    for (int k0 = 0; k0 < K; k0 += 32) {
        if (EPI == 0) {
            const float* A = (const float*)Av;
            *reinterpret_cast<uint4*>(&As[arow][aseg * 8]) =
                cvt8(A + (size_t)(m0 + arow) * K + k0 + aseg * 8);
        } else {
            const __hip_bfloat16* A = (const __hip_bfloat16*)Av;
            *reinterpret_cast<uint4*>(&As[arow][aseg * 8]) =
                *reinterpret_cast<const uint4*>(
                    A + (size_t)(m0 + arow) * K + k0 + aseg * 8);
        }

        const float* bp = Bw + (size_t)(k0 + brow) * N + n0 + bseg * 8;
        float4 b0 = *reinterpret_cast<const float4*>(bp);
        float4 b1 = *reinterpret_cast<const float4*>(bp + 4);
        Bs[bseg * 8 + 0][brow] = __float2bfloat16(b0.x);
        Bs[bseg * 8 + 1][brow] = __float2bfloat16(b0.y);
        Bs[bseg * 8 + 2][brow] = __float2bfloat16(b0.z);
        Bs[bseg * 8 + 3][brow] = __float2bfloat16(b0.w);
        Bs[bseg * 8 + 4][brow] = __float2bfloat16(b1.x);
        Bs[bseg * 8 + 5][brow] = __float2bfloat16(b1.y);
        Bs[bseg * 8 + 6][brow] = __float2bfloat16(b1.z);
        Bs[bseg * 8 + 7][brow] = __float2bfloat16(b1.w);

        __syncthreads();

        short8 af[2], bf[2];
#pragma unroll
        for (int mm = 0; mm < 2; ++mm)
            af[mm] = *reinterpret_cast<const short8*>(&As[mb + mm * 16 + l16][quad * 8]);
#pragma unroll
        for (int nn = 0; nn < 2; ++nn)
            bf[nn] = *reinterpret_cast<const short8*>(&Bs[nb + nn * 16 + l16][quad * 8]);
#pragma unroll
        for (int mm = 0; mm < 2; ++mm)
#pragma unroll
            for (int nn = 0; nn < 2; ++nn)
                acc[mm][nn] = __builtin_amdgcn_mfma_f32_16x16x32_bf16(
                    af[mm], bf[nn], acc[mm][nn], 0, 0, 0);

        __syncthreads();
    }

#pragma unroll
    for (int mm = 0; mm < 2; ++mm) {
#pragma unroll
        for (int nn = 0; nn < 2; ++nn) {
            const int col = n0 + nb + nn * 16 + l16;
            const float bsv = bias[col];
#pragma unroll
            for (int r = 0; r < 4; ++r) {
                const int row = m0 + mb + mm * 16 + quad * 4 + r;
                const float v = acc[mm][nn][r] + bsv;
                if (EPI == 0) {
                    const int seg = col >> 10;      // 0=q, 1=k, 2=v
                    const int c = col & 1023;
                    if (seg == 0) {
                        out0[(size_t)row * 1024 + c] = v;   // q fp32, row-major
                    } else {
                        const int b = row >> 10, s = row & 1023;
                        const int h = c >> 6, d = c & 63;
                        const size_t idx =
                            ((size_t)((b * 16 + h) * 1024 + s)) * 64 + d;
                        if (seg == 1) present[idx] = v;
                        else          present[HEAD_ELEMS + idx] = v;
                    }
                } else {
                    out0[(size_t)row * N + col] = v;
                }
            }
        }
    }
}

// ---------------------------------------------------------------------------
// Causal flash attention. One block per (64-row q-tile, head, batch).
// qbuf fp32 [b*1024+s][h*64+d] (ld 1024); present fp32 [2][b][h][s][d];
// a_ws bf16 [b*1024+s][h*64+d] (ld 1024).
// ---------------------------------------------------------------------------
__global__ __launch_bounds__(256) void attn64(
    const float* __restrict__ qbuf,
    const float* __restrict__ present,
    __hip_bfloat16* __restrict__ a_ws)
{
    const int qt = blockIdx.x, h = blockIdx.y, b = blockIdx.z;
    const int tid  = threadIdx.x;
    const int wave = tid >> 6, lane = tid & 63;
    const int quad = lane >> 4, l16 = lane & 15;
    const int mb = (wave >> 1) * 32, nb = (wave & 1) * 32;

    const size_t headoff = ((size_t)(b * 16 + h)) * Ssz * HDc;
    const float* Qb = qbuf + ((size_t)(b * Ssz + qt * 64)) * NXc + h * 64;
    const float* Kp = present + headoff;
    const float* Vp = present + HEAD_ELEMS + headoff;

    __shared__ __align__(16) __hip_bfloat16 Qs[64][72];
    __shared__ __align__(16) __hip_bfloat16 Ks[64][72];  // [key][d]
    __shared__ __align__(16) __hip_bfloat16 Vts[64][72]; // [d][key]
    __shared__ __align__(16) __hip_bfloat16 Ps[64][72];  // [q][key]
    __shared__ float Sc[64][65];
    __shared__ float mrow[64], lrow[64], arw[64];

    // Load + convert Q tile: 64 rows x 8 segs of 8
#pragma unroll
    for (int it = 0; it < 2; ++it) {
        const int c = tid + it * 256;
        const int row = c >> 3, seg = c & 7;
        *reinterpret_cast<uint4*>(&Qs[row][seg * 8]) =
            cvt8(Qb + (size_t)row * NXc + seg * 8);
    }
    if (tid < 64) { mrow[tid] = -1e9f; lrow[tid] = 0.f; }

    floatx4 oacc[2][2];
#pragma unroll
    for (int i = 0; i < 2; ++i)
#pragma unroll
        for (int j = 0; j < 2; ++j)
#pragma unroll
            for (int r = 0; r < 4; ++r) oacc[i][j][r] = 0.f;

    __syncthreads();

    for (int kt = 0; kt <= qt; ++kt) {
        // Stage K tile and transposed V tile (fp32 -> bf16)
#pragma unroll
        for (int it = 0; it < 2; ++it) {
            const int c = tid + it * 256;
            const int row = c >> 3, seg = c & 7;
            *reinterpret_cast<uint4*>(&Ks[row][seg * 8]) =
                cvt8(Kp + (size_t)(kt * 64 + row) * 64 + seg * 8);
            const float* vp = Vp + (size_t)(kt * 64 + row) * 64 + seg * 8;
            float4 v0 = *reinterpret_cast<const float4*>(vp);
            float4 v1 = *reinterpret_cast<const float4*>(vp + 4);
            Vts[seg * 8 + 0][row] = __float2bfloat16(v0.x);
            Vts[seg * 8 + 1][row] = __float2bfloat16(v0.y);
            Vts[seg * 8 + 2][row] = __float2bfloat16(v0.z);
            Vts[seg * 8 + 3][row] = __float2bfloat16(v0.w);
            Vts[seg * 8 + 4][row] = __float2bfloat16(v1.x);
            Vts[seg * 8 + 5][row] = __float2bfloat16(v1.y);
            Vts[seg * 8 + 6][row] = __float2bfloat16(v1.z);
            Vts[seg * 8 + 7][row] = __float2bfloat16(v1.w);
        }
        __syncthreads();

        // S = Q K^T
        floatx4 sacc[2][2];
#pragma unroll
        for (int i = 0; i < 2; ++i)
#pragma unroll
            for (int j = 0; j < 2; ++j)
#pragma unroll
                for (int r = 0; r < 4; ++r) sacc[i][j][r] = 0.f;
#pragma unroll
        for (int kd = 0; kd < 64; kd += 32) {
            short8 af[2], bf[2];
#pragma unroll
            for (int mm = 0; mm < 2; ++mm)
                af[mm] = *reinterpret_cast<const short8*>(
                    &Qs[mb + mm * 16 + l16][kd + quad * 8]);
#pragma unroll
            for (int nn = 0; nn < 2; ++nn)
                bf[nn] = *reinterpret_cast<const short8*>(
                    &Ks[nb + nn * 16 + l16][kd + quad * 8]);
#pragma unroll
            for (int mm = 0; mm < 2; ++mm)
#pragma unroll
                for (int nn = 0; nn < 2; ++nn)
                    sacc[mm][nn] = __builtin_amdgcn_mfma_f32_16x16x32_bf16(
                        af[mm], bf[nn], sacc[mm][nn], 0, 0, 0);
        }

        const bool diag = (kt == qt);
#pragma unroll
        for (int mm = 0; mm < 2; ++mm)
#pragma unroll
            for (int nn = 0; nn < 2; ++nn)
#pragma unroll
                for (int r = 0; r < 4; ++r) {
                    const int row = mb + mm * 16 + quad * 4 + r;
                    const int col = nb + nn * 16 + l16;
                    float v = fminf(fmaxf(sacc[mm][nn][r] * 0.125f, -1e8f), 1e8f);
                    if (diag && col > row) v = -1e9f;  // causal mask
                    Sc[row][col] = v;
                }
        __syncthreads();

        // Online softmax, one lane per q row
        if (tid < 64) {
            const int r = tid;
            const float mo = mrow[r];
            float mx = mo;
            for (int c = 0; c < 64; ++c) mx = fmaxf(mx, Sc[r][c]);
            const float al = (mo <= -5e8f) ? 0.f : __expf(mo - mx);
            float sum = 0.f;
            for (int c = 0; c < 64; ++c) {
                const float sv = Sc[r][c];
                const float p = (sv <= -5e8f) ? 0.f : __expf(sv - mx);
                sum += p;
                Ps[r][c] = __float2bfloat16(p);
            }
            mrow[r] = mx;
            lrow[r] = lrow[r] * al + sum;
            arw[r]  = al;
        }
        __syncthreads();

        // O *= alpha ; O += P V
#pragma unroll
        for (int mm = 0; mm < 2; ++mm) {
            const int rbase = mb + mm * 16 + quad * 4;
#pragma unroll
            for (int r = 0; r < 4; ++r) {
                const float al = arw[rbase + r];
                oacc[mm][0][r] *= al;
                oacc[mm][1][r] *= al;
            }
        }
#pragma unroll
        for (int kk = 0; kk < 64; kk += 32) {
            short8 pf[2], vf[2];
#pragma unroll
            for (int mm = 0; mm < 2; ++mm)
                pf[mm] = *reinterpret_cast<const short8*>(
                    &Ps[mb + mm * 16 + l16][kk + quad * 8]);
#pragma unroll
            for (int nn = 0; nn < 2; ++nn)
                vf[nn] = *reinterpret_cast<const short8*>(
                    &Vts[nb + nn * 16 + l16][kk + quad * 8]);
#pragma unroll
            for (int mm = 0; mm < 2; ++mm)
#pragma unroll
                for (int nn = 0; nn < 2; ++nn)
                    oacc[mm][nn] = __builtin_amdgcn_mfma_f32_16x16x32_bf16(
                        pf[mm], vf[nn], oacc[mm][nn], 0, 0, 0);
        }
        __syncthreads();
    }

    // O / l -> a_ws (bf16)
#pragma unroll
    for (int mm = 0; mm < 2; ++mm) {
#pragma unroll
        for (int nn = 0; nn < 2; ++nn) {
#pragma unroll
            for (int r = 0; r < 4; ++r) {
                const int row = mb + mm * 16 + quad * 4 + r;
                const int col = nb + nn * 16 + l16;
                const float inv = 1.0f / fmaxf(lrow[row], 1e-20f);
                a_ws[((size_t)(b * Ssz + qt * 64 + row)) * NXc + h * 64 + col] =
                    __float2bfloat16(oacc[mm][nn][r] * inv);
            }
        }
    }
}

extern "C" void kernel_launch(void* const* d_in, const int* in_sizes, int n_in,
                              void* d_out, int out_size, void* d_ws, size_t ws_size,
                              hipStream_t stream) {
    const float* x      = (const float*)d_in[0];
    const float* w_attn = (const float*)d_in[1];
    const float* b_attn = (const float*)d_in[2];
    const float* w_proj = (const float*)d_in[3];
    const float* b_proj = (const float*)d_in[4];
    // d_in[5] = causal_bias (unused; mask is structural)

    float* out     = (float*)d_out;
    float* present = out + OUT_ELEMS;                 // k then v, fp32
    __hip_bfloat16* a_ws = (__hip_bfloat16*)d_ws;     // 8 MB bf16

    hipMemsetAsync(d_ws, 0, (size_t)OUT_ELEMS * sizeof(__hip_bfloat16), stream);

    // 1) QKV: x(4096x1024) @ w_attn(1024x3072) + b_attn
    //    q -> out region (fp32 scratch until proj overwrites), k/v -> present
    dim3 g1(3072 / 64, 4096 / 64);
    gemm64<0><<<g1, 256, 0, stream>>>(x, w_attn, b_attn, out, present,
                                      4096, 3072, 1024);

    // 2) causal flash attention; a -> ws (bf16)
    dim3 g2(Ssz / 64, NHc, Bsz);
    attn64<<<g2, 256, 0, stream>>>(out, present, a_ws);

    // 3) out = a @ w_proj + b_proj
    dim3 g3(1024 / 64, 4096 / 64);
    gemm64<1><<<g3, 256, 0, stream>>>(a_ws, w_proj, b_proj, out, nullptr,
                                      4096, 1024, 1024);
}

// Round 4
// 253.624 us; speedup vs baseline: 1.4889x; 1.4889x over previous
//
#include <hip/hip_runtime.h>
#include <hip/hip_bf16.h>

typedef __attribute__((ext_vector_type(8))) short short8;
typedef __attribute__((ext_vector_type(4))) float floatx4;

constexpr int Bsz = 4, Ssz = 1024, NXc = 1024, NHc = 16, HDc = 64;
constexpr int OUT_ELEMS  = Bsz * Ssz * NXc;        // 4194304
constexpr int HEAD_ELEMS = Bsz * NHc * Ssz * HDc;  // 4194304

union BF8 { __hip_bfloat16 h[8]; uint4 v; };

__device__ __forceinline__ uint4 cvt8(const float* __restrict__ p) {
    float4 a = *reinterpret_cast<const float4*>(p);
    float4 b = *reinterpret_cast<const float4*>(p + 4);
    BF8 u;
    u.h[0] = __float2bfloat16(a.x); u.h[1] = __float2bfloat16(a.y);
    u.h[2] = __float2bfloat16(a.z); u.h[3] = __float2bfloat16(a.w);
    u.h[4] = __float2bfloat16(b.x); u.h[5] = __float2bfloat16(b.y);
    u.h[6] = __float2bfloat16(b.z); u.h[7] = __float2bfloat16(b.w);
    return u.v;
}

// async 16B global -> LDS (wave-uniform LDS base + lane*16)
__device__ __forceinline__ void load_lds_16B(const void* g, void* l) {
    __builtin_amdgcn_global_load_lds(
        (const __attribute__((address_space(1))) unsigned int*)g,
        (__attribute__((address_space(3))) unsigned int*)l, 16, 0, 0);
}

// ===========================================================================
// FAST PATH
// ===========================================================================

// fp32 -> bf16 straight convert, 8 elems/thread
__global__ __launch_bounds__(256) void cvt_kernel(
    const float* __restrict__ in, __hip_bfloat16* __restrict__ out, int n)
{
    int i = (blockIdx.x * 256 + threadIdx.x) * 8;
    if (i < n)
        *reinterpret_cast<uint4*>(out + i) = cvt8(in + i);
}

// K x N fp32  ->  N x K bf16 (transpose + convert), 64x64 tiles
__global__ __launch_bounds__(256) void transpose_cvt(
    const float* __restrict__ in, __hip_bfloat16* __restrict__ out,
    int K, int N)
{
    __shared__ float t[64][65];
    const int tid = threadIdx.x;
    const int k0 = blockIdx.y * 64, n0 = blockIdx.x * 64;
#pragma unroll
    for (int j = 0; j < 16; ++j) {
        const int idx = tid + j * 256;
        const int row = idx >> 6, col = idx & 63;
        t[row][col] = in[(size_t)(k0 + row) * N + n0 + col];
    }
    __syncthreads();
#pragma unroll
    for (int j = 0; j < 16; ++j) {
        const int idx = tid + j * 256;
        const int orow = idx >> 6, ocol = idx & 63;   // orow = n, ocol = k
        out[(size_t)(n0 + orow) * K + k0 + ocol] = __float2bfloat16(t[ocol][orow]);
    }
}

// ---------------------------------------------------------------------------
// 128x128-tile bf16 GEMM, BK=32, global_load_lds staging (m97 structure).
// A: M x K bf16 row-major (ld K). Bt: N x K bf16 row-major (ld K).
// EPI==0: QKV epilogue: q -> qws bf16 (ld 1024); k/v -> present fp32.
// EPI==1: plain fp32 row-major epilogue (ld N).
// ---------------------------------------------------------------------------
template <int EPI>
__global__ __launch_bounds__(256) void gemm128(
    const __hip_bfloat16* __restrict__ A,
    const __hip_bfloat16* __restrict__ Bt,
    const float* __restrict__ bias,
    float* __restrict__ outf,
    __hip_bfloat16* __restrict__ qws,
    float* __restrict__ present,
    int M, int N, int K)
{
    __shared__ __align__(16) __hip_bfloat16 As[128 * 32];
    __shared__ __align__(16) __hip_bfloat16 Bs[128 * 32];

    const int tid  = threadIdx.x;
    const int w    = tid >> 6, lane = tid & 63;
    const int quad = lane >> 4, l16 = lane & 15;
    const int m0 = blockIdx.y * 128, n0 = blockIdx.x * 128;
    const int mb = (w >> 1) * 64, nbw = (w & 1) * 64;

    const int srow = lane >> 2;       // 0..15 within a 16-row chunk
    const int skseg = (lane & 3) * 8; // k offset in elements

    floatx4 acc[4][4];
#pragma unroll
    for (int i = 0; i < 4; ++i)
#pragma unroll
        for (int j = 0; j < 4; ++j)
#pragma unroll
            for (int r = 0; r < 4; ++r) acc[i][j][r] = 0.f;

    for (int k0 = 0; k0 < K; k0 += 32) {
        // stage A tile (128x32) and B tile (128x32): per wave 2 calls each
#pragma unroll
        for (int c = 0; c < 2; ++c) {
            const int chunk = w * 2 + c;          // 0..7, 16 rows each
            const int row = chunk * 16 + srow;
            load_lds_16B(A + (size_t)(m0 + row) * K + k0 + skseg,
                         &As[chunk * 512]);
            load_lds_16B(Bt + (size_t)(n0 + row) * K + k0 + skseg,
                         &Bs[chunk * 512]);
        }
        __syncthreads();

        short8 af[4], bfr[4];
#pragma unroll
        for (int mi = 0; mi < 4; ++mi)
            af[mi] = *reinterpret_cast<const short8*>(
                &As[(mb + mi * 16 + l16) * 32 + quad * 8]);
#pragma unroll
        for (int ni = 0; ni < 4; ++ni)
            bfr[ni] = *reinterpret_cast<const short8*>(
                &Bs[(nbw + ni * 16 + l16) * 32 + quad * 8]);
#pragma unroll
        for (int mi = 0; mi < 4; ++mi)
#pragma unroll
            for (int ni = 0; ni < 4; ++ni)
                acc[mi][ni] = __builtin_amdgcn_mfma_f32_16x16x32_bf16(
                    af[mi], bfr[ni], acc[mi][ni], 0, 0, 0);

        __syncthreads();
    }

#pragma unroll
    for (int mi = 0; mi < 4; ++mi) {
#pragma unroll
        for (int ni = 0; ni < 4; ++ni) {
            const int col = n0 + nbw + ni * 16 + l16;
            const float bsv = bias[col];
#pragma unroll
            for (int r = 0; r < 4; ++r) {
                const int row = m0 + mb + mi * 16 + quad * 4 + r;
                const float v = acc[mi][ni][r] + bsv;
                if (EPI == 0) {
                    const int seg = col >> 10;  // 0=q 1=k 2=v
                    const int c = col & 1023;
                    if (seg == 0) {
                        qws[(size_t)row * 1024 + c] = __float2bfloat16(v);
                    } else {
                        const int b = row >> 10, s = row & 1023;
                        const int h = c >> 6, d = c & 63;
                        const size_t idx =
                            ((size_t)((b * 16 + h) * 1024 + s)) * 64 + d;
                        if (seg == 1) present[idx] = v;
                        else          present[HEAD_ELEMS + idx] = v;
                    }
                } else {
                    outf[(size_t)row * N + col] = v;
                }
            }
        }
    }
}

// ---------------------------------------------------------------------------
// Causal flash attention, parallel online softmax (4 lanes per q-row).
// qws bf16 [b*1024+s][h*64+d] (ld 1024); present fp32 [2][b][h][s][d];
// a_ws bf16 [b*1024+s][h*64+d] (ld 1024).
// ---------------------------------------------------------------------------
__global__ __launch_bounds__(256) void attn_fast(
    const __hip_bfloat16* __restrict__ qws,
    const float* __restrict__ present,
    __hip_bfloat16* __restrict__ a_ws)
{
    const int qt = blockIdx.x, h = blockIdx.y, b = blockIdx.z;
    const int tid  = threadIdx.x;
    const int wave = tid >> 6, lane = tid & 63;
    const int quad = lane >> 4, l16 = lane & 15;
    const int mb = (wave >> 1) * 32, nb = (wave & 1) * 32;

    const size_t headoff = ((size_t)(b * 16 + h)) * Ssz * HDc;
    const __hip_bfloat16* Qb = qws + ((size_t)(b * Ssz + qt * 64)) * NXc + h * 64;
    const float* Kp = present + headoff;
    const float* Vp = present + HEAD_ELEMS + headoff;

    __shared__ __align__(16) __hip_bfloat16 Qs[64][72];
    __shared__ __align__(16) __hip_bfloat16 Ks[64][72];  // [key][d]
    __shared__ __align__(16) __hip_bfloat16 Vts[64][72]; // [d][key]
    __shared__ __align__(16) __hip_bfloat16 Ps[64][72];  // [q][key]
    __shared__ float Sc[64][65];
    __shared__ float mrow[64], lrow[64], arw[64];

#pragma unroll
    for (int it = 0; it < 2; ++it) {
        const int c = tid + it * 256;
        const int row = c >> 3, seg = c & 7;
        *reinterpret_cast<uint4*>(&Qs[row][seg * 8]) =
            *reinterpret_cast<const uint4*>(Qb + (size_t)row * NXc + seg * 8);
    }
    if (tid < 64) { mrow[tid] = -1e9f; lrow[tid] = 0.f; }

    floatx4 oacc[2][2];
#pragma unroll
    for (int i = 0; i < 2; ++i)
#pragma unroll
        for (int j = 0; j < 2; ++j)
#pragma unroll
            for (int r = 0; r < 4; ++r) oacc[i][j][r] = 0.f;

    __syncthreads();

    for (int kt = 0; kt <= qt; ++kt) {
#pragma unroll
        for (int it = 0; it < 2; ++it) {
            const int c = tid + it * 256;
            const int row = c >> 3, seg = c & 7;
            *reinterpret_cast<uint4*>(&Ks[row][seg * 8]) =
                cvt8(Kp + (size_t)(kt * 64 + row) * 64 + seg * 8);
            const float* vp = Vp + (size_t)(kt * 64 + row) * 64 + seg * 8;
            float4 v0 = *reinterpret_cast<const float4*>(vp);
            float4 v1 = *reinterpret_cast<const float4*>(vp + 4);
            Vts[seg * 8 + 0][row] = __float2bfloat16(v0.x);
            Vts[seg * 8 + 1][row] = __float2bfloat16(v0.y);
            Vts[seg * 8 + 2][row] = __float2bfloat16(v0.z);
            Vts[seg * 8 + 3][row] = __float2bfloat16(v0.w);
            Vts[seg * 8 + 4][row] = __float2bfloat16(v1.x);
            Vts[seg * 8 + 5][row] = __float2bfloat16(v1.y);
            Vts[seg * 8 + 6][row] = __float2bfloat16(v1.z);
            Vts[seg * 8 + 7][row] = __float2bfloat16(v1.w);
        }
        __syncthreads();

        // S = Q K^T
        floatx4 sacc[2][2];
#pragma unroll
        for (int i = 0; i < 2; ++i)
#pragma unroll
            for (int j = 0; j < 2; ++j)
#pragma unroll
                for (int r = 0; r < 4; ++r) sacc[i][j][r] = 0.f;
#pragma unroll
        for (int kd = 0; kd < 64; kd += 32) {
            short8 af[2], bf[2];
#pragma unroll
            for (int mm = 0; mm < 2; ++mm)
                af[mm] = *reinterpret_cast<const short8*>(
                    &Qs[mb + mm * 16 + l16][kd + quad * 8]);
#pragma unroll
            for (int nn = 0; nn < 2; ++nn)
                bf[nn] = *reinterpret_cast<const short8*>(
                    &Ks[nb + nn * 16 + l16][kd + quad * 8]);
#pragma unroll
            for (int mm = 0; mm < 2; ++mm)
#pragma unroll
                for (int nn = 0; nn < 2; ++nn)
                    sacc[mm][nn] = __builtin_amdgcn_mfma_f32_16x16x32_bf16(
                        af[mm], bf[nn], sacc[mm][nn], 0, 0, 0);
        }

        const bool diag = (kt == qt);
#pragma unroll
        for (int mm = 0; mm < 2; ++mm)
#pragma unroll
            for (int nn = 0; nn < 2; ++nn)
#pragma unroll
                for (int r = 0; r < 4; ++r) {
                    const int row = mb + mm * 16 + quad * 4 + r;
                    const int col = nb + nn * 16 + l16;
                    float v = sacc[mm][nn][r] * 0.125f;
                    if (diag && col > row) v = -1e9f;
                    Sc[row][col] = v;
                }
        __syncthreads();

        // parallel online softmax: 4 lanes per row, 16 cols each
        {
            const int r = tid >> 2, part = tid & 3;
            const int cbase = part * 16;
            float mx = -1e30f;
#pragma unroll
            for (int c = 0; c < 16; ++c) mx = fmaxf(mx, Sc[r][cbase + c]);
            mx = fmaxf(mx, __shfl_xor(mx, 1));
            mx = fmaxf(mx, __shfl_xor(mx, 2));
            const float mo = mrow[r];
            const float mnew = fmaxf(mo, mx);
            float sum = 0.f;
#pragma unroll
            for (int c = 0; c < 16; ++c) {
                const float p = __expf(Sc[r][cbase + c] - mnew);
                sum += p;
                Ps[r][cbase + c] = __float2bfloat16(p);
            }
            sum += __shfl_xor(sum, 1);
            sum += __shfl_xor(sum, 2);
            if (part == 0) {
                const float al = __expf(mo - mnew);
                mrow[r] = mnew;
                lrow[r] = lrow[r] * al + sum;
                arw[r]  = al;
            }
        }
        __syncthreads();

        // O *= alpha ; O += P V
#pragma unroll
        for (int mm = 0; mm < 2; ++mm) {
            const int rbase = mb + mm * 16 + quad * 4;
#pragma unroll
            for (int r = 0; r < 4; ++r) {
                const float al = arw[rbase + r];
                oacc[mm][0][r] *= al;
                oacc[mm][1][r] *= al;
            }
        }
#pragma unroll
        for (int kk = 0; kk < 64; kk += 32) {
            short8 pf[2], vf[2];
#pragma unroll
            for (int mm = 0; mm < 2; ++mm)
                pf[mm] = *reinterpret_cast<const short8*>(
                    &Ps[mb + mm * 16 + l16][kk + quad * 8]);
#pragma unroll
            for (int nn = 0; nn < 2; ++nn)
                vf[nn] = *reinterpret_cast<const short8*>(
                    &Vts[nb + nn * 16 + l16][kk + quad * 8]);
#pragma unroll
            for (int mm = 0; mm < 2; ++mm)
#pragma unroll
                for (int nn = 0; nn < 2; ++nn)
                    oacc[mm][nn] = __builtin_amdgcn_mfma_f32_16x16x32_bf16(
                        pf[mm], vf[nn], oacc[mm][nn], 0, 0, 0);
        }
        __syncthreads();
    }

#pragma unroll
    for (int mm = 0; mm < 2; ++mm)
#pragma unroll
        for (int nn = 0; nn < 2; ++nn)
#pragma unroll
            for (int r = 0; r < 4; ++r) {
                const int row = mb + mm * 16 + quad * 4 + r;
                const int col = nb + nn * 16 + l16;
                const float inv = 1.0f / fmaxf(lrow[row], 1e-20f);
                a_ws[((size_t)(b * Ssz + qt * 64 + row)) * NXc + h * 64 + col] =
                    __float2bfloat16(oacc[mm][nn][r] * inv);
            }
}

// ===========================================================================
// FALLBACK PATH (round-3, known-passing; used if ws_size < 32 MB)
// ===========================================================================
template <int EPI>
__global__ __launch_bounds__(256) void gemm64(
    const void* __restrict__ Av, const float* __restrict__ Bw,
    const float* __restrict__ bias, float* __restrict__ out0,
    float* __restrict__ present, int M, int N, int K)
{
    __shared__ __align__(16) __hip_bfloat16 As[64][40];
    __shared__ __align__(16) __hip_bfloat16 Bs[64][40];
    const int tid = threadIdx.x;
    const int wave = tid >> 6, lane = tid & 63;
    const int quad = lane >> 4, l16 = lane & 15;
    const int m0 = blockIdx.y * 64, n0 = blockIdx.x * 64;
    const int mb = (wave >> 1) * 32, nb = (wave & 1) * 32;
    const int arow = tid >> 2, aseg = tid & 3;
    const int brow = tid >> 3, bseg = tid & 7;
    floatx4 acc[2][2];
#pragma unroll
    for (int i = 0; i < 2; ++i)
#pragma unroll
        for (int j = 0; j < 2; ++j)
#pragma unroll
            for (int r = 0; r < 4; ++r) acc[i][j][r] = 0.f;
    for (int k0 = 0; k0 < K; k0 += 32) {
        if (EPI == 0) {
            const float* A = (const float*)Av;
            *reinterpret_cast<uint4*>(&As[arow][aseg * 8]) =
                cvt8(A + (size_t)(m0 + arow) * K + k0 + aseg * 8);
        } else {
            const __hip_bfloat16* A = (const __hip_bfloat16*)Av;
            *reinterpret_cast<uint4*>(&As[arow][aseg * 8]) =
                *reinterpret_cast<const uint4*>(
                    A + (size_t)(m0 + arow) * K + k0 + aseg * 8);
        }
        const float* bp = Bw + (size_t)(k0 + brow) * N + n0 + bseg * 8;
        float4 b0 = *reinterpret_cast<const float4*>(bp);
        float4 b1 = *reinterpret_cast<const float4*>(bp + 4);
        Bs[bseg * 8 + 0][brow] = __float2bfloat16(b0.x);
        Bs[bseg * 8 + 1][brow] = __float2bfloat16(b0.y);
        Bs[bseg * 8 + 2][brow] = __float2bfloat16(b0.z);
        Bs[bseg * 8 + 3][brow] = __float2bfloat16(b0.w);
        Bs[bseg * 8 + 4][brow] = __float2bfloat16(b1.x);
        Bs[bseg * 8 + 5][brow] = __float2bfloat16(b1.y);
        Bs[bseg * 8 + 6][brow] = __float2bfloat16(b1.z);
        Bs[bseg * 8 + 7][brow] = __float2bfloat16(b1.w);
        __syncthreads();
        short8 af[2], bf[2];
#pragma unroll
        for (int mm = 0; mm < 2; ++mm)
            af[mm] = *reinterpret_cast<const short8*>(&As[mb + mm * 16 + l16][quad * 8]);
#pragma unroll
        for (int nn = 0; nn < 2; ++nn)
            bf[nn] = *reinterpret_cast<const short8*>(&Bs[nb + nn * 16 + l16][quad * 8]);
#pragma unroll
        for (int mm = 0; mm < 2; ++mm)
#pragma unroll
            for (int nn = 0; nn < 2; ++nn)
                acc[mm][nn] = __builtin_amdgcn_mfma_f32_16x16x32_bf16(
                    af[mm], bf[nn], acc[mm][nn], 0, 0, 0);
        __syncthreads();
    }
#pragma unroll
    for (int mm = 0; mm < 2; ++mm)
#pragma unroll
        for (int nn = 0; nn < 2; ++nn) {
            const int col = n0 + nb + nn * 16 + l16;
            const float bsv = bias[col];
#pragma unroll
            for (int r = 0; r < 4; ++r) {
                const int row = m0 + mb + mm * 16 + quad * 4 + r;
                const float v = acc[mm][nn][r] + bsv;
                if (EPI == 0) {
                    const int seg = col >> 10;
                    const int c = col & 1023;
                    if (seg == 0) out0[(size_t)row * 1024 + c] = v;
                    else {
                        const int b = row >> 10, s = row & 1023;
                        const int h = c >> 6, d = c & 63;
                        const size_t idx = ((size_t)((b * 16 + h) * 1024 + s)) * 64 + d;
                        if (seg == 1) present[idx] = v;
                        else          present[HEAD_ELEMS + idx] = v;
                    }
                } else out0[(size_t)row * N + col] = v;
            }
        }
}

__global__ __launch_bounds__(256) void attn64(
    const float* __restrict__ qbuf, const float* __restrict__ present,
    __hip_bfloat16* __restrict__ a_ws)
{
    const int qt = blockIdx.x, h = blockIdx.y, b = blockIdx.z;
    const int tid = threadIdx.x;
    const int wave = tid >> 6, lane = tid & 63;
    const int quad = lane >> 4, l16 = lane & 15;
    const int mb = (wave >> 1) * 32, nb = (wave & 1) * 32;
    const size_t headoff = ((size_t)(b * 16 + h)) * Ssz * HDc;
    const float* Qb = qbuf + ((size_t)(b * Ssz + qt * 64)) * NXc + h * 64;
    const float* Kp = present + headoff;
    const float* Vp = present + HEAD_ELEMS + headoff;
    __shared__ __align__(16) __hip_bfloat16 Qs[64][72];
    __shared__ __align__(16) __hip_bfloat16 Ks[64][72];
    __shared__ __align__(16) __hip_bfloat16 Vts[64][72];
    __shared__ __align__(16) __hip_bfloat16 Ps[64][72];
    __shared__ float Sc[64][65];
    __shared__ float mrow[64], lrow[64], arw[64];
#pragma unroll
    for (int it = 0; it < 2; ++it) {
        const int c = tid + it * 256;
        const int row = c >> 3, seg = c & 7;
        *reinterpret_cast<uint4*>(&Qs[row][seg * 8]) =
            cvt8(Qb + (size_t)row * NXc + seg * 8);
    }
    if (tid < 64) { mrow[tid] = -1e9f; lrow[tid] = 0.f; }
    floatx4 oacc[2][2];
#pragma unroll
    for (int i = 0; i < 2; ++i)
#pragma unroll
        for (int j = 0; j < 2; ++j)
#pragma unroll
            for (int r = 0; r < 4; ++r) oacc[i][j][r] = 0.f;
    __syncthreads();
    for (int kt = 0; kt <= qt; ++kt) {
#pragma unroll
        for (int it = 0; it < 2; ++it) {
            const int c = tid + it * 256;
            const int row = c >> 3, seg = c & 7;
            *reinterpret_cast<uint4*>(&Ks[row][seg * 8]) =
                cvt8(Kp + (size_t)(kt * 64 + row) * 64 + seg * 8);
            const float* vp = Vp + (size_t)(kt * 64 + row) * 64 + seg * 8;
            float4 v0 = *reinterpret_cast<const float4*>(vp);
            float4 v1 = *reinterpret_cast<const float4*>(vp + 4);
            Vts[seg * 8 + 0][row] = __float2bfloat16(v0.x);
            Vts[seg * 8 + 1][row] = __float2bfloat16(v0.y);
            Vts[seg * 8 + 2][row] = __float2bfloat16(v0.z);
            Vts[seg * 8 + 3][row] = __float2bfloat16(v0.w);
            Vts[seg * 8 + 4][row] = __float2bfloat16(v1.x);
            Vts[seg * 8 + 5][row] = __float2bfloat16(v1.y);
            Vts[seg * 8 + 6][row] = __float2bfloat16(v1.z);
            Vts[seg * 8 + 7][row] = __float2bfloat16(v1.w);
        }
        __syncthreads();
        floatx4 sacc[2][2];
#pragma unroll
        for (int i = 0; i < 2; ++i)
#pragma unroll
            for (int j = 0; j < 2; ++j)
#pragma unroll
                for (int r = 0; r < 4; ++r) sacc[i][j][r] = 0.f;
#pragma unroll
        for (int kd = 0; kd < 64; kd += 32) {
            short8 af[2], bf[2];
#pragma unroll
            for (int mm = 0; mm < 2; ++mm)
                af[mm] = *reinterpret_cast<const short8*>(&Qs[mb + mm * 16 + l16][kd + quad * 8]);
#pragma unroll
            for (int nn = 0; nn < 2; ++nn)
                bf[nn] = *reinterpret_cast<const short8*>(&Ks[nb + nn * 16 + l16][kd + quad * 8]);
#pragma unroll
            for (int mm = 0; mm < 2; ++mm)
#pragma unroll
                for (int nn = 0; nn < 2; ++nn)
                    sacc[mm][nn] = __builtin_amdgcn_mfma_f32_16x16x32_bf16(
                        af[mm], bf[nn], sacc[mm][nn], 0, 0, 0);
        }
        const bool diag = (kt == qt);
#pragma unroll
        for (int mm = 0; mm < 2; ++mm)
#pragma unroll
            for (int nn = 0; nn < 2; ++nn)
#pragma unroll
                for (int r = 0; r < 4; ++r) {
                    const int row = mb + mm * 16 + quad * 4 + r;
                    const int col = nb + nn * 16 + l16;
                    float v = fminf(fmaxf(sacc[mm][nn][r] * 0.125f, -1e8f), 1e8f);
                    if (diag && col > row) v = -1e9f;
                    Sc[row][col] = v;
                }
        __syncthreads();
        if (tid < 64) {
            const int r = tid;
            const float mo = mrow[r];
            float mx = mo;
            for (int c = 0; c < 64; ++c) mx = fmaxf(mx, Sc[r][c]);
            const float al = (mo <= -5e8f) ? 0.f : __expf(mo - mx);
            float sum = 0.f;
            for (int c = 0; c < 64; ++c) {
                const float sv = Sc[r][c];
                const float p = (sv <= -5e8f) ? 0.f : __expf(sv - mx);
                sum += p;
                Ps[r][c] = __float2bfloat16(p);
            }
            mrow[r] = mx;
            lrow[r] = lrow[r] * al + sum;
            arw[r]  = al;
        }
        __syncthreads();
#pragma unroll
        for (int mm = 0; mm < 2; ++mm) {
            const int rbase = mb + mm * 16 + quad * 4;
#pragma unroll
            for (int r = 0; r < 4; ++r) {
                const float al = arw[rbase + r];
                oacc[mm][0][r] *= al;
                oacc[mm][1][r] *= al;
            }
        }
#pragma unroll
        for (int kk = 0; kk < 64; kk += 32) {
            short8 pf[2], vf[2];
#pragma unroll
            for (int mm = 0; mm < 2; ++mm)
                pf[mm] = *reinterpret_cast<const short8*>(&Ps[mb + mm * 16 + l16][kk + quad * 8]);
#pragma unroll
            for (int nn = 0; nn < 2; ++nn)
                vf[nn] = *reinterpret_cast<const short8*>(&Vts[nb + nn * 16 + l16][kk + quad * 8]);
#pragma unroll
            for (int mm = 0; mm < 2; ++mm)
#pragma unroll
                for (int nn = 0; nn < 2; ++nn)
                    oacc[mm][nn] = __builtin_amdgcn_mfma_f32_16x16x32_bf16(
                        pf[mm], vf[nn], oacc[mm][nn], 0, 0, 0);
        }
        __syncthreads();
    }
#pragma unroll
    for (int mm = 0; mm < 2; ++mm)
#pragma unroll
        for (int nn = 0; nn < 2; ++nn)
#pragma unroll
            for (int r = 0; r < 4; ++r) {
                const int row = mb + mm * 16 + quad * 4 + r;
                const int col = nb + nn * 16 + l16;
                const float inv = 1.0f / fmaxf(lrow[row], 1e-20f);
                a_ws[((size_t)(b * Ssz + qt * 64 + row)) * NXc + h * 64 + col] =
                    __float2bfloat16(oacc[mm][nn][r] * inv);
            }
}

// ===========================================================================
extern "C" void kernel_launch(void* const* d_in, const int* in_sizes, int n_in,
                              void* d_out, int out_size, void* d_ws, size_t ws_size,
                              hipStream_t stream) {
    const float* x      = (const float*)d_in[0];
    const float* w_attn = (const float*)d_in[1];
    const float* b_attn = (const float*)d_in[2];
    const float* w_proj = (const float*)d_in[3];
    const float* b_proj = (const float*)d_in[4];

    float* out     = (float*)d_out;
    float* present = out + OUT_ELEMS;

    const size_t NEED = 32u * 1024u * 1024u;
    if (ws_size >= NEED) {
        // ws layout (bf16 elems): a_ws[4M] | q_ws[4M] | x_bf[4M] | wTa[3M] | wTp[1M]
        __hip_bfloat16* a_ws = (__hip_bfloat16*)d_ws;
        __hip_bfloat16* q_ws = a_ws + 4194304;
        __hip_bfloat16* x_bf = q_ws + 4194304;
        __hip_bfloat16* wTa  = x_bf + 4194304;
        __hip_bfloat16* wTp  = wTa + 3145728;

        cvt_kernel<<<2048, 256, 0, stream>>>(x, x_bf, OUT_ELEMS);
        transpose_cvt<<<dim3(48, 16), 256, 0, stream>>>(w_attn, wTa, 1024, 3072);
        transpose_cvt<<<dim3(16, 16), 256, 0, stream>>>(w_proj, wTp, 1024, 1024);

        gemm128<0><<<dim3(24, 32), 256, 0, stream>>>(
            x_bf, wTa, b_attn, nullptr, q_ws, present, 4096, 3072, 1024);

        attn_fast<<<dim3(16, 16, 4), 256, 0, stream>>>(q_ws, present, a_ws);

        gemm128<1><<<dim3(8, 32), 256, 0, stream>>>(
            a_ws, wTp, b_proj, out, nullptr, nullptr, 4096, 1024, 1024);
    } else {
        // round-3 fallback (needs 8 MB ws)
        __hip_bfloat16* a_ws = (__hip_bfloat16*)d_ws;
        hipMemsetAsync(d_ws, 0, (size_t)OUT_ELEMS * sizeof(__hip_bfloat16), stream);
        gemm64<0><<<dim3(48, 64), 256, 0, stream>>>(x, w_attn, b_attn, out, present,
                                                    4096, 3072, 1024);
        attn64<<<dim3(16, 16, 4), 256, 0, stream>>>(out, present, a_ws);
        gemm64<1><<<dim3(16, 64), 256, 0, stream>>>(a_ws, w_proj, b_proj, out, nullptr,
                                                    4096, 1024, 1024);
    }
}

// Round 5
// 232.011 us; speedup vs baseline: 1.6276x; 1.0932x over previous
//
#include <hip/hip_runtime.h>
#include <hip/hip_bf16.h>

typedef __attribute__((ext_vector_type(8))) short short8;
typedef __attribute__((ext_vector_type(4))) float floatx4;

constexpr int Bsz = 4, Ssz = 1024, NXc = 1024, NHc = 16, HDc = 64;
constexpr int OUT_ELEMS  = Bsz * Ssz * NXc;        // 4194304
constexpr int HEAD_ELEMS = Bsz * NHc * Ssz * HDc;  // 4194304

union BF8 { __hip_bfloat16 h[8]; uint4 v; short8 s; };

__device__ __forceinline__ uint4 cvt8(const float* __restrict__ p) {
    float4 a = *reinterpret_cast<const float4*>(p);
    float4 b = *reinterpret_cast<const float4*>(p + 4);
    BF8 u;
    u.h[0] = __float2bfloat16(a.x); u.h[1] = __float2bfloat16(a.y);
    u.h[2] = __float2bfloat16(a.z); u.h[3] = __float2bfloat16(a.w);
    u.h[4] = __float2bfloat16(b.x); u.h[5] = __float2bfloat16(b.y);
    u.h[6] = __float2bfloat16(b.z); u.h[7] = __float2bfloat16(b.w);
    return u.v;
}

// async 16B global -> LDS (wave-uniform LDS base + lane*16)
__device__ __forceinline__ void load_lds_16B(const void* g, void* l) {
    __builtin_amdgcn_global_load_lds(
        (const __attribute__((address_space(1))) unsigned int*)g,
        (__attribute__((address_space(3))) unsigned int*)l, 16, 0, 0);
}

// ===========================================================================
// FAST PATH
// ===========================================================================

__global__ __launch_bounds__(256) void cvt_kernel(
    const float* __restrict__ in, __hip_bfloat16* __restrict__ out, int n)
{
    int i = (blockIdx.x * 256 + threadIdx.x) * 8;
    if (i < n)
        *reinterpret_cast<uint4*>(out + i) = cvt8(in + i);
}

// K x N fp32  ->  N x K bf16 (transpose + convert), 64x64 tiles
__global__ __launch_bounds__(256) void transpose_cvt(
    const float* __restrict__ in, __hip_bfloat16* __restrict__ out,
    int K, int N)
{
    __shared__ float t[64][65];
    const int tid = threadIdx.x;
    const int k0 = blockIdx.y * 64, n0 = blockIdx.x * 64;
#pragma unroll
    for (int j = 0; j < 16; ++j) {
        const int idx = tid + j * 256;
        const int row = idx >> 6, col = idx & 63;
        t[row][col] = in[(size_t)(k0 + row) * N + n0 + col];
    }
    __syncthreads();
#pragma unroll
    for (int j = 0; j < 16; ++j) {
        const int idx = tid + j * 256;
        const int orow = idx >> 6, ocol = idx & 63;
        out[(size_t)(n0 + orow) * K + k0 + ocol] = __float2bfloat16(t[ocol][orow]);
    }
}

// ---------------------------------------------------------------------------
// 128x128-tile bf16 GEMM, BK=32, global_load_lds staging (m97 structure).
// ---------------------------------------------------------------------------
template <int EPI>
__global__ __launch_bounds__(256) void gemm128(
    const __hip_bfloat16* __restrict__ A,
    const __hip_bfloat16* __restrict__ Bt,
    const float* __restrict__ bias,
    float* __restrict__ outf,
    __hip_bfloat16* __restrict__ qws,
    float* __restrict__ present,
    int M, int N, int K)
{
    __shared__ __align__(16) __hip_bfloat16 As[128 * 32];
    __shared__ __align__(16) __hip_bfloat16 Bs[128 * 32];

    const int tid  = threadIdx.x;
    const int w    = tid >> 6, lane = tid & 63;
    const int quad = lane >> 4, l16 = lane & 15;
    const int m0 = blockIdx.y * 128, n0 = blockIdx.x * 128;
    const int mb = (w >> 1) * 64, nbw = (w & 1) * 64;

    const int srow = lane >> 2;
    const int skseg = (lane & 3) * 8;

    floatx4 acc[4][4];
#pragma unroll
    for (int i = 0; i < 4; ++i)
#pragma unroll
        for (int j = 0; j < 4; ++j)
#pragma unroll
            for (int r = 0; r < 4; ++r) acc[i][j][r] = 0.f;

    for (int k0 = 0; k0 < K; k0 += 32) {
#pragma unroll
        for (int c = 0; c < 2; ++c) {
            const int chunk = w * 2 + c;
            const int row = chunk * 16 + srow;
            load_lds_16B(A + (size_t)(m0 + row) * K + k0 + skseg,
                         &As[chunk * 512]);
            load_lds_16B(Bt + (size_t)(n0 + row) * K + k0 + skseg,
                         &Bs[chunk * 512]);
        }
        __syncthreads();

        short8 af[4], bfr[4];
#pragma unroll
        for (int mi = 0; mi < 4; ++mi)
            af[mi] = *reinterpret_cast<const short8*>(
                &As[(mb + mi * 16 + l16) * 32 + quad * 8]);
#pragma unroll
        for (int ni = 0; ni < 4; ++ni)
            bfr[ni] = *reinterpret_cast<const short8*>(
                &Bs[(nbw + ni * 16 + l16) * 32 + quad * 8]);
#pragma unroll
        for (int mi = 0; mi < 4; ++mi)
#pragma unroll
            for (int ni = 0; ni < 4; ++ni)
                acc[mi][ni] = __builtin_amdgcn_mfma_f32_16x16x32_bf16(
                    af[mi], bfr[ni], acc[mi][ni], 0, 0, 0);

        __syncthreads();
    }

#pragma unroll
    for (int mi = 0; mi < 4; ++mi) {
#pragma unroll
        for (int ni = 0; ni < 4; ++ni) {
            const int col = n0 + nbw + ni * 16 + l16;
            const float bsv = bias[col];
#pragma unroll
            for (int r = 0; r < 4; ++r) {
                const int row = m0 + mb + mi * 16 + quad * 4 + r;
                const float v = acc[mi][ni][r] + bsv;
                if (EPI == 0) {
                    const int seg = col >> 10;  // 0=q 1=k 2=v
                    const int c = col & 1023;
                    if (seg == 0) {
                        qws[(size_t)row * 1024 + c] = __float2bfloat16(v);
                    } else {
                        const int b = row >> 10, s = row & 1023;
                        const int h = c >> 6, d = c & 63;
                        const size_t idx =
                            ((size_t)((b * 16 + h) * 1024 + s)) * 64 + d;
                        if (seg == 1) present[idx] = v;
                        else          present[HEAD_ELEMS + idx] = v;
                    }
                } else {
                    outf[(size_t)row * N + col] = v;
                }
            }
        }
    }
}

// ---------------------------------------------------------------------------
// Causal flash attention v2. One block per (bx, head, batch); each block
// handles q-tiles {8+bx, 7-bx} (uniform 17 kv-tile-iterations).
// Wave owns 16 q-rows; softmax fully in-register (shfl butterflies);
// Q in registers; V staged transposed via coalesced column loads.
// ---------------------------------------------------------------------------
__global__ __launch_bounds__(256) void attn_v2(
    const __hip_bfloat16* __restrict__ qws,
    const float* __restrict__ present,
    __hip_bfloat16* __restrict__ a_ws)
{
    const int bx = blockIdx.x, h = blockIdx.y, b = blockIdx.z;
    const int tid  = threadIdx.x;
    const int wave = tid >> 6, lane = tid & 63;
    const int quad = lane >> 4, l16 = lane & 15;
    const int stripe = wave * 16;                 // wave's 16 q-rows in 64-tile

    const size_t headoff = ((size_t)(b * 16 + h)) * Ssz * HDc;
    const float* Kp = present + headoff;
    const float* Vp = present + HEAD_ELEMS + headoff;

    __shared__ __align__(16) __hip_bfloat16 Ks[64][72];   // [key][d]
    __shared__ __align__(16) __hip_bfloat16 Vts[64][72];  // [d][key]
    __shared__ __align__(16) __hip_bfloat16 Ps[64][72];   // [q][key]

    // staging roles
    const int krow = tid >> 3, kseg = tid & 7;     // K: (key-row, d-seg)
    const int vd = tid & 63, vg = tid >> 6;        // V: (d, key-group)

#pragma unroll
    for (int pass = 0; pass < 2; ++pass) {
        const int qt = (pass == 0) ? (8 + bx) : (7 - bx);

        // Q fragments in registers: rows stripe+l16, k = kd + quad*8
        const __hip_bfloat16* Qb =
            qws + ((size_t)(b * Ssz + qt * 64 + stripe + l16)) * NXc + h * 64;
        short8 qf0 = *reinterpret_cast<const short8*>(Qb + quad * 8);
        short8 qf1 = *reinterpret_cast<const short8*>(Qb + 32 + quad * 8);

        float m_i[4], l_i[4];
#pragma unroll
        for (int r = 0; r < 4; ++r) { m_i[r] = -1e9f; l_i[r] = 0.f; }
        floatx4 oacc[4];
#pragma unroll
        for (int ni = 0; ni < 4; ++ni)
#pragma unroll
            for (int r = 0; r < 4; ++r) oacc[ni][r] = 0.f;

        for (int kt = 0; kt <= qt; ++kt) {
            // ---- stage K (row-chunks) and V (transposed, column loads) ----
#pragma unroll
            for (int it = 0; it < 2; ++it) {
                const int kr = krow + it * 32;
                *reinterpret_cast<uint4*>(&Ks[kr][kseg * 8]) =
                    cvt8(Kp + (size_t)(kt * 64 + kr) * 64 + kseg * 8);

                const int kb = (it * 4 + vg) * 8;  // key base for V column
                BF8 u;
#pragma unroll
                for (int i = 0; i < 8; ++i)
                    u.h[i] = __float2bfloat16(
                        Vp[(size_t)(kt * 64 + kb + i) * 64 + vd]);
                *reinterpret_cast<uint4*>(&Vts[vd][kb]) = u.v;
            }
            __syncthreads();

            // ---- S = Q K^T : wave's 16 rows x 64 keys ----
            floatx4 sacc[4];
#pragma unroll
            for (int ni = 0; ni < 4; ++ni)
#pragma unroll
                for (int r = 0; r < 4; ++r) sacc[ni][r] = 0.f;
#pragma unroll
            for (int ni = 0; ni < 4; ++ni) {
                short8 kf0 = *reinterpret_cast<const short8*>(
                    &Ks[ni * 16 + l16][quad * 8]);
                short8 kf1 = *reinterpret_cast<const short8*>(
                    &Ks[ni * 16 + l16][32 + quad * 8]);
                sacc[ni] = __builtin_amdgcn_mfma_f32_16x16x32_bf16(
                    qf0, kf0, sacc[ni], 0, 0, 0);
                sacc[ni] = __builtin_amdgcn_mfma_f32_16x16x32_bf16(
                    qf1, kf1, sacc[ni], 0, 0, 0);
            }

            // ---- in-register online softmax (per lane: 4 rows) ----
            const bool diag = (kt == qt);
            float alpha_[4];
#pragma unroll
            for (int r = 0; r < 4; ++r) {
                const int lrow = stripe + quad * 4 + r;
                float sv[4];
                float mx = -1e30f;
#pragma unroll
                for (int ni = 0; ni < 4; ++ni) {
                    float v = sacc[ni][r] * 0.125f;     // 1/sqrt(64)
                    if (diag && (ni * 16 + l16) > lrow) v = -1e9f;
                    sv[ni] = v;
                    mx = fmaxf(mx, v);
                }
                mx = fmaxf(mx, __shfl_xor(mx, 1));
                mx = fmaxf(mx, __shfl_xor(mx, 2));
                mx = fmaxf(mx, __shfl_xor(mx, 4));
                mx = fmaxf(mx, __shfl_xor(mx, 8));
                const float mnew = fmaxf(m_i[r], mx);
                const float al = __expf(m_i[r] - mnew);
                m_i[r] = mnew;
                float s = 0.f;
#pragma unroll
                for (int nn = 0; nn < 4; ++nn) {
                    const int ni = (nn + quad) & 3;     // bank-rotated stores
                    const float p = __expf(sv[ni] - mnew);
                    s += p;
                    Ps[lrow][ni * 16 + l16] = __float2bfloat16(p);
                }
                s += __shfl_xor(s, 1);
                s += __shfl_xor(s, 2);
                s += __shfl_xor(s, 4);
                s += __shfl_xor(s, 8);
                l_i[r] = l_i[r] * al + s;
                alpha_[r] = al;
            }

            // rescale O (registers only)
#pragma unroll
            for (int ni = 0; ni < 4; ++ni)
#pragma unroll
                for (int r = 0; r < 4; ++r) oacc[ni][r] *= alpha_[r];

            // ---- O += P V : Ps rows written+read by this wave (no barrier) ----
#pragma unroll
            for (int kk = 0; kk < 64; kk += 32) {
                short8 pf = *reinterpret_cast<const short8*>(
                    &Ps[stripe + l16][kk + quad * 8]);
#pragma unroll
                for (int ni = 0; ni < 4; ++ni) {
                    short8 vf = *reinterpret_cast<const short8*>(
                        &Vts[ni * 16 + l16][kk + quad * 8]);
                    oacc[ni] = __builtin_amdgcn_mfma_f32_16x16x32_bf16(
                        pf, vf, oacc[ni], 0, 0, 0);
                }
            }
            __syncthreads();   // protect Ks/Vts before next staging
        }

        // ---- epilogue: O / l -> a_ws ----
#pragma unroll
        for (int ni = 0; ni < 4; ++ni) {
#pragma unroll
            for (int r = 0; r < 4; ++r) {
                const int row = qt * 64 + stripe + quad * 4 + r;
                const int col = h * 64 + ni * 16 + l16;
                const float inv = 1.0f / fmaxf(l_i[r], 1e-20f);
                a_ws[((size_t)(b * Ssz + row)) * NXc + col] =
                    __float2bfloat16(oacc[ni][r] * inv);
            }
        }
    }
}

// ===========================================================================
// FALLBACK PATH (round-3, known-passing; used if ws_size < 32 MB)
// ===========================================================================
template <int EPI>
__global__ __launch_bounds__(256) void gemm64(
    const void* __restrict__ Av, const float* __restrict__ Bw,
    const float* __restrict__ bias, float* __restrict__ out0,
    float* __restrict__ present, int M, int N, int K)
{
    __shared__ __align__(16) __hip_bfloat16 As[64][40];
    __shared__ __align__(16) __hip_bfloat16 Bs[64][40];
    const int tid = threadIdx.x;
    const int wave = tid >> 6, lane = tid & 63;
    const int quad = lane >> 4, l16 = lane & 15;
    const int m0 = blockIdx.y * 64, n0 = blockIdx.x * 64;
    const int mb = (wave >> 1) * 32, nb = (wave & 1) * 32;
    const int arow = tid >> 2, aseg = tid & 3;
    const int brow = tid >> 3, bseg = tid & 7;
    floatx4 acc[2][2];
#pragma unroll
    for (int i = 0; i < 2; ++i)
#pragma unroll
        for (int j = 0; j < 2; ++j)
#pragma unroll
            for (int r = 0; r < 4; ++r) acc[i][j][r] = 0.f;
    for (int k0 = 0; k0 < K; k0 += 32) {
        if (EPI == 0) {
            const float* A = (const float*)Av;
            *reinterpret_cast<uint4*>(&As[arow][aseg * 8]) =
                cvt8(A + (size_t)(m0 + arow) * K + k0 + aseg * 8);
        } else {
            const __hip_bfloat16* A = (const __hip_bfloat16*)Av;
            *reinterpret_cast<uint4*>(&As[arow][aseg * 8]) =
                *reinterpret_cast<const uint4*>(
                    A + (size_t)(m0 + arow) * K + k0 + aseg * 8);
        }
        const float* bp = Bw + (size_t)(k0 + brow) * N + n0 + bseg * 8;
        float4 b0 = *reinterpret_cast<const float4*>(bp);
        float4 b1 = *reinterpret_cast<const float4*>(bp + 4);
        Bs[bseg * 8 + 0][brow] = __float2bfloat16(b0.x);
        Bs[bseg * 8 + 1][brow] = __float2bfloat16(b0.y);
        Bs[bseg * 8 + 2][brow] = __float2bfloat16(b0.z);
        Bs[bseg * 8 + 3][brow] = __float2bfloat16(b0.w);
        Bs[bseg * 8 + 4][brow] = __float2bfloat16(b1.x);
        Bs[bseg * 8 + 5][brow] = __float2bfloat16(b1.y);
        Bs[bseg * 8 + 6][brow] = __float2bfloat16(b1.z);
        Bs[bseg * 8 + 7][brow] = __float2bfloat16(b1.w);
        __syncthreads();
        short8 af[2], bf[2];
#pragma unroll
        for (int mm = 0; mm < 2; ++mm)
            af[mm] = *reinterpret_cast<const short8*>(&As[mb + mm * 16 + l16][quad * 8]);
#pragma unroll
        for (int nn = 0; nn < 2; ++nn)
            bf[nn] = *reinterpret_cast<const short8*>(&Bs[nb + nn * 16 + l16][quad * 8]);
#pragma unroll
        for (int mm = 0; mm < 2; ++mm)
#pragma unroll
            for (int nn = 0; nn < 2; ++nn)
                acc[mm][nn] = __builtin_amdgcn_mfma_f32_16x16x32_bf16(
                    af[mm], bf[nn], acc[mm][nn], 0, 0, 0);
        __syncthreads();
    }
#pragma unroll
    for (int mm = 0; mm < 2; ++mm)
#pragma unroll
        for (int nn = 0; nn < 2; ++nn) {
            const int col = n0 + nb + nn * 16 + l16;
            const float bsv = bias[col];
#pragma unroll
            for (int r = 0; r < 4; ++r) {
                const int row = m0 + mb + mm * 16 + quad * 4 + r;
                const float v = acc[mm][nn][r] + bsv;
                if (EPI == 0) {
                    const int seg = col >> 10;
                    const int c = col & 1023;
                    if (seg == 0) out0[(size_t)row * 1024 + c] = v;
                    else {
                        const int b = row >> 10, s = row & 1023;
                        const int h = c >> 6, d = c & 63;
                        const size_t idx = ((size_t)((b * 16 + h) * 1024 + s)) * 64 + d;
                        if (seg == 1) present[idx] = v;
                        else          present[HEAD_ELEMS + idx] = v;
                    }
                } else out0[(size_t)row * N + col] = v;
            }
        }
}

__global__ __launch_bounds__(256) void attn64(
    const float* __restrict__ qbuf, const float* __restrict__ present,
    __hip_bfloat16* __restrict__ a_ws)
{
    const int qt = blockIdx.x, h = blockIdx.y, b = blockIdx.z;
    const int tid = threadIdx.x;
    const int wave = tid >> 6, lane = tid & 63;
    const int quad = lane >> 4, l16 = lane & 15;
    const int mb = (wave >> 1) * 32, nb = (wave & 1) * 32;
    const size_t headoff = ((size_t)(b * 16 + h)) * Ssz * HDc;
    const float* Qb = qbuf + ((size_t)(b * Ssz + qt * 64)) * NXc + h * 64;
    const float* Kp = present + headoff;
    const float* Vp = present + HEAD_ELEMS + headoff;
    __shared__ __align__(16) __hip_bfloat16 Qs[64][72];
    __shared__ __align__(16) __hip_bfloat16 Ks[64][72];
    __shared__ __align__(16) __hip_bfloat16 Vts[64][72];
    __shared__ __align__(16) __hip_bfloat16 Ps[64][72];
    __shared__ float Sc[64][65];
    __shared__ float mrow[64], lrow[64], arw[64];
#pragma unroll
    for (int it = 0; it < 2; ++it) {
        const int c = tid + it * 256;
        const int row = c >> 3, seg = c & 7;
        *reinterpret_cast<uint4*>(&Qs[row][seg * 8]) =
            cvt8(Qb + (size_t)row * NXc + seg * 8);
    }
    if (tid < 64) { mrow[tid] = -1e9f; lrow[tid] = 0.f; }
    floatx4 oacc[2][2];
#pragma unroll
    for (int i = 0; i < 2; ++i)
#pragma unroll
        for (int j = 0; j < 2; ++j)
#pragma unroll
            for (int r = 0; r < 4; ++r) oacc[i][j][r] = 0.f;
    __syncthreads();
    for (int kt = 0; kt <= qt; ++kt) {
#pragma unroll
        for (int it = 0; it < 2; ++it) {
            const int c = tid + it * 256;
            const int row = c >> 3, seg = c & 7;
            *reinterpret_cast<uint4*>(&Ks[row][seg * 8]) =
                cvt8(Kp + (size_t)(kt * 64 + row) * 64 + seg * 8);
            const float* vp = Vp + (size_t)(kt * 64 + row) * 64 + seg * 8;
            float4 v0 = *reinterpret_cast<const float4*>(vp);
            float4 v1 = *reinterpret_cast<const float4*>(vp + 4);
            Vts[seg * 8 + 0][row] = __float2bfloat16(v0.x);
            Vts[seg * 8 + 1][row] = __float2bfloat16(v0.y);
            Vts[seg * 8 + 2][row] = __float2bfloat16(v0.z);
            Vts[seg * 8 + 3][row] = __float2bfloat16(v0.w);
            Vts[seg * 8 + 4][row] = __float2bfloat16(v1.x);
            Vts[seg * 8 + 5][row] = __float2bfloat16(v1.y);
            Vts[seg * 8 + 6][row] = __float2bfloat16(v1.z);
            Vts[seg * 8 + 7][row] = __float2bfloat16(v1.w);
        }
        __syncthreads();
        floatx4 sacc[2][2];
#pragma unroll
        for (int i = 0; i < 2; ++i)
#pragma unroll
            for (int j = 0; j < 2; ++j)
#pragma unroll
                for (int r = 0; r < 4; ++r) sacc[i][j][r] = 0.f;
#pragma unroll
        for (int kd = 0; kd < 64; kd += 32) {
            short8 af[2], bf[2];
#pragma unroll
            for (int mm = 0; mm < 2; ++mm)
                af[mm] = *reinterpret_cast<const short8*>(&Qs[mb + mm * 16 + l16][kd + quad * 8]);
#pragma unroll
            for (int nn = 0; nn < 2; ++nn)
                bf[nn] = *reinterpret_cast<const short8*>(&Ks[nb + nn * 16 + l16][kd + quad * 8]);
#pragma unroll
            for (int mm = 0; mm < 2; ++mm)
#pragma unroll
                for (int nn = 0; nn < 2; ++nn)
                    sacc[mm][nn] = __builtin_amdgcn_mfma_f32_16x16x32_bf16(
                        af[mm], bf[nn], sacc[mm][nn], 0, 0, 0);
        }
        const bool diag = (kt == qt);
#pragma unroll
        for (int mm = 0; mm < 2; ++mm)
#pragma unroll
            for (int nn = 0; nn < 2; ++nn)
#pragma unroll
                for (int r = 0; r < 4; ++r) {
                    const int row = mb + mm * 16 + quad * 4 + r;
                    const int col = nb + nn * 16 + l16;
                    float v = fminf(fmaxf(sacc[mm][nn][r] * 0.125f, -1e8f), 1e8f);
                    if (diag && col > row) v = -1e9f;
                    Sc[row][col] = v;
                }
        __syncthreads();
        if (tid < 64) {
            const int r = tid;
            const float mo = mrow[r];
            float mx = mo;
            for (int c = 0; c < 64; ++c) mx = fmaxf(mx, Sc[r][c]);
            const float al = (mo <= -5e8f) ? 0.f : __expf(mo - mx);
            float sum = 0.f;
            for (int c = 0; c < 64; ++c) {
                const float sv = Sc[r][c];
                const float p = (sv <= -5e8f) ? 0.f : __expf(sv - mx);
                sum += p;
                Ps[r][c] = __float2bfloat16(p);
            }
            mrow[r] = mx;
            lrow[r] = lrow[r] * al + sum;
            arw[r]  = al;
        }
        __syncthreads();
#pragma unroll
        for (int mm = 0; mm < 2; ++mm) {
            const int rbase = mb + mm * 16 + quad * 4;
#pragma unroll
            for (int r = 0; r < 4; ++r) {
                const float al = arw[rbase + r];
                oacc[mm][0][r] *= al;
                oacc[mm][1][r] *= al;
            }
        }
#pragma unroll
        for (int kk = 0; kk < 64; kk += 32) {
            short8 pf[2], vf[2];
#pragma unroll
            for (int mm = 0; mm < 2; ++mm)
                pf[mm] = *reinterpret_cast<const short8*>(&Ps[mb + mm * 16 + l16][kk + quad * 8]);
#pragma unroll
            for (int nn = 0; nn < 2; ++nn)
                vf[nn] = *reinterpret_cast<const short8*>(&Vts[nb + nn * 16 + l16][kk + quad * 8]);
#pragma unroll
            for (int mm = 0; mm < 2; ++mm)
#pragma unroll
                for (int nn = 0; nn < 2; ++nn)
                    oacc[mm][nn] = __builtin_amdgcn_mfma_f32_16x16x32_bf16(
                        pf[mm], vf[nn], oacc[mm][nn], 0, 0, 0);
        }
        __syncthreads();
    }
#pragma unroll
    for (int mm = 0; mm < 2; ++mm)
#pragma unroll
        for (int nn = 0; nn < 2; ++nn)
#pragma unroll
            for (int r = 0; r < 4; ++r) {
                const int row = mb + mm * 16 + quad * 4 + r;
                const int col = nb + nn * 16 + l16;
                const float inv = 1.0f / fmaxf(lrow[row], 1e-20f);
                a_ws[((size_t)(b * Ssz + qt * 64 + row)) * NXc + h * 64 + col] =
                    __float2bfloat16(oacc[mm][nn][r] * inv);
            }
}

// ===========================================================================
extern "C" void kernel_launch(void* const* d_in, const int* in_sizes, int n_in,
                              void* d_out, int out_size, void* d_ws, size_t ws_size,
                              hipStream_t stream) {
    const float* x      = (const float*)d_in[0];
    const float* w_attn = (const float*)d_in[1];
    const float* b_attn = (const float*)d_in[2];
    const float* w_proj = (const float*)d_in[3];
    const float* b_proj = (const float*)d_in[4];

    float* out     = (float*)d_out;
    float* present = out + OUT_ELEMS;

    const size_t NEED = 32u * 1024u * 1024u;
    if (ws_size >= NEED) {
        // ws layout (bf16 elems): a_ws[4M] | q_ws[4M] | x_bf[4M] | wTa[3M] | wTp[1M]
        __hip_bfloat16* a_ws = (__hip_bfloat16*)d_ws;
        __hip_bfloat16* q_ws = a_ws + 4194304;
        __hip_bfloat16* x_bf = q_ws + 4194304;
        __hip_bfloat16* wTa  = x_bf + 4194304;
        __hip_bfloat16* wTp  = wTa + 3145728;

        cvt_kernel<<<2048, 256, 0, stream>>>(x, x_bf, OUT_ELEMS);
        transpose_cvt<<<dim3(48, 16), 256, 0, stream>>>(w_attn, wTa, 1024, 3072);
        transpose_cvt<<<dim3(16, 16), 256, 0, stream>>>(w_proj, wTp, 1024, 1024);

        gemm128<0><<<dim3(24, 32), 256, 0, stream>>>(
            x_bf, wTa, b_attn, nullptr, q_ws, present, 4096, 3072, 1024);

        attn_v2<<<dim3(8, 16, 4), 256, 0, stream>>>(q_ws, present, a_ws);

        gemm128<1><<<dim3(8, 32), 256, 0, stream>>>(
            a_ws, wTp, b_proj, out, nullptr, nullptr, 4096, 1024, 1024);
    } else {
        // round-3 fallback (needs 8 MB ws)
        __hip_bfloat16* a_ws = (__hip_bfloat16*)d_ws;
        hipMemsetAsync(d_ws, 0, (size_t)OUT_ELEMS * sizeof(__hip_bfloat16), stream);
        gemm64<0><<<dim3(48, 64), 256, 0, stream>>>(x, w_attn, b_attn, out, present,
                                                    4096, 3072, 1024);
        attn64<<<dim3(16, 16, 4), 256, 0, stream>>>(out, present, a_ws);
        gemm64<1><<<dim3(16, 64), 256, 0, stream>>>(a_ws, w_proj, b_proj, out, nullptr,
                                                    4096, 1024, 1024);
    }
}